// Round 4
// baseline (283.045 us; speedup 1.0000x reference)
//
#include <hip/hip_runtime.h>

#define B_AGENTS 262144
#define NN 17
#define BLOCK 256
#define CHUNK_FLOATS (BLOCK * NN)        // 4352 floats = 17408 B per matrix
#define CHUNK4 (CHUNK_FLOATS / 4)        // 1088 float4
#define NCHUNKS (B_AGENTS * NN / BLOCK)  // 17408 chunks
#define GRID 2176                        // 17408 / 2176 = exactly 8 chunks/block

__global__ __launch_bounds__(BLOCK) void grossberg_kernel(
    const float* __restrict__ state,
    const float* __restrict__ W_pos,
    const float* __restrict__ W_neg,
    const float* __restrict__ feas,
    const float* __restrict__ pert,
    float* __restrict__ out)
{
    __shared__ float lwp[CHUNK_FLOATS];
    __shared__ float lwn[CHUNK_FLOATS];

    const int tid = threadIdx.x;
    const bool tail = (tid < CHUNK4 - 4 * BLOCK);   // 64 tail float4s per matrix

    // ---- register double-buffer: prologue load of first chunk ----
    float4 rp[5], rn[5];
    int c = blockIdx.x;
    {
        const float4* __restrict__ gp = (const float4*)W_pos + (size_t)c * CHUNK4;
        const float4* __restrict__ gn = (const float4*)W_neg + (size_t)c * CHUNK4;
        #pragma unroll
        for (int it = 0; it < 4; ++it) { rp[it] = gp[tid + it * BLOCK]; rn[it] = gn[tid + it * BLOCK]; }
        if (tail) { rp[4] = gp[tid + 4 * BLOCK]; rn[4] = gn[tid + 4 * BLOCK]; }
    }

    for (; c < NCHUNKS; c += GRID) {
        const int t = c * BLOCK + tid;          // global (agent,row) item
        const int b = t / NN;                   // magic-multiply
        const int i = t - b * NN;

        // issue state loads early: latency hides under the two barriers below
        float sv[NN];
        const float* __restrict__ s = state + b * NN;
        #pragma unroll
        for (int j = 0; j < NN; ++j) sv[j] = s[j];

        __syncthreads();                        // LDS free (prev compute done)

        // staged registers -> LDS
        float4* lp = (float4*)lwp;
        float4* ln = (float4*)lwn;
        #pragma unroll
        for (int it = 0; it < 4; ++it) { lp[tid + it * BLOCK] = rp[it]; ln[tid + it * BLOCK] = rn[it]; }
        if (tail) { lp[tid + 4 * BLOCK] = rp[4]; ln[tid + 4 * BLOCK] = rn[4]; }

        __syncthreads();                        // LDS ready

        // issue NEXT chunk's global loads; in flight during compute below
        const int cn = c + GRID;
        if (cn < NCHUNKS) {
            const float4* __restrict__ gp = (const float4*)W_pos + (size_t)cn * CHUNK4;
            const float4* __restrict__ gn = (const float4*)W_neg + (size_t)cn * CHUNK4;
            #pragma unroll
            for (int it = 0; it < 4; ++it) { rp[it] = gp[tid + it * BLOCK]; rn[it] = gn[tid + it * BLOCK]; }
            if (tail) { rp[4] = gp[tid + 4 * BLOCK]; rn[4] = gn[tid + 4 * BLOCK]; }
        }

        // ---- dot products from LDS (17l+j mod 32 -> 2 lanes/bank = free) ----
        const float* wpr = lwp + tid * NN;
        const float* wnr = lwn + tid * NN;
        float sum_p = 0.f, sum_n = 0.f;
        #pragma unroll
        for (int j = 0; j < NN; ++j) {
            sum_p = fmaf(wpr[j], sv[j], sum_p);
            sum_n = fmaf(wnr[j], sv[j], sum_n);
        }

        // ---- gating / env / lateral / mask ----
        float gate_e = 1.f, gate_i = 1.f;
        float env_e = 0.f, env_i = 0.f;
        float lat = 0.f, mask = 1.f;

        if (i < 9) {
            const float p = pert[b * NN + i];
            env_e = fmaxf(p, 0.f);
            env_i = fmaxf(-p, 0.f);
        } else if (i < 13) {
            const float v = sv[i + 4] + pert[b * NN + i + 4];   // valences_eval[i-9]
            gate_e = 1.f / (1.f + __expf(-1.5f * v));           // sigmoid(ALPHA*v)
            gate_i = 1.f / (1.f + __expf(0.75f * v));           // sigmoid(-BETA*v)
            const float sum_act = sv[9] + sv[10] + sv[11] + sv[12];
            const float other = sum_act - sv[i];
            lat = 3.0f * other / (0.3f + other + 1e-6f);        // LAT_INHIB/(DIV_SIGMA+..)
            mask = feas[b * 4 + (i - 9)];
        }

        const float te = gate_e * sum_p + env_e;
        const float ti = gate_i * sum_n + lat + env_i;
        const float si = sv[i];

        const float dS = (-0.15f * si
                          + (1.0f - si) * fmaxf(te, 0.f)
                          - (0.1f + si) * fmaxf(ti, 0.f)) * 1.25f;   // /TAU

        out[t] = dS * mask;
    }
}

extern "C" void kernel_launch(void* const* d_in, const int* in_sizes, int n_in,
                              void* d_out, int out_size, void* d_ws, size_t ws_size,
                              hipStream_t stream)
{
    // setup_inputs order: t, state, W_pos, W_neg, feasibility, perturbation
    const float* state = (const float*)d_in[1];
    const float* W_pos = (const float*)d_in[2];
    const float* W_neg = (const float*)d_in[3];
    const float* feas  = (const float*)d_in[4];
    const float* pert  = (const float*)d_in[5];
    float* out = (float*)d_out;

    grossberg_kernel<<<GRID, BLOCK, 0, stream>>>(state, W_pos, W_neg, feas, pert, out);
}

// Round 5
// 117.459 us; speedup vs baseline: 2.4097x; 2.4097x over previous
//
#include <hip/hip_runtime.h>

#define B_AGENTS 262144
#define NN 17

__global__ __launch_bounds__(256) void grossberg_kernel(
    const float* __restrict__ state,
    const float* __restrict__ W_pos,
    const float* __restrict__ W_neg,
    const float* __restrict__ feas,
    const float* __restrict__ pert,
    float* __restrict__ out)
{
    const int t = blockIdx.x * blockDim.x + threadIdx.x;
    const int total = B_AGENTS * NN;
    if (t >= total) return;

    const int b = t / NN;            // magic-multiply
    const int i = t - b * NN;

    // --- issue the long-pole W streams first (max memory-level parallelism).
    // Rows are 68 B, contiguous per thread; L1 merges the wave's lane spread.
    const float* __restrict__ wp = W_pos + (size_t)b * (NN * NN) + i * NN;
    const float* __restrict__ wn = W_neg + (size_t)b * (NN * NN) + i * NN;
    float wpv[NN], wnv[NN];
    #pragma unroll
    for (int j = 0; j < NN; ++j) { wpv[j] = wp[j]; wnv[j] = wn[j]; }

    // --- agent state vector (17x L1-shared across the agent's threads)
    const float* __restrict__ s = state + b * NN;
    float sv[NN];
    #pragma unroll
    for (int j = 0; j < NN; ++j) sv[j] = s[j];

    float sum_p = 0.f, sum_n = 0.f;
    #pragma unroll
    for (int j = 0; j < NN; ++j) {
        sum_p = fmaf(wpv[j], sv[j], sum_p);
        sum_n = fmaf(wnv[j], sv[j], sum_n);
    }

    // --- gating / env / lateral / mask ---
    float gate_e = 1.f, gate_i = 1.f;
    float env_e = 0.f, env_i = 0.f;
    float lat = 0.f, mask = 1.f;

    if (i < 9) {
        const float p = pert[b * NN + i];
        env_e = fmaxf(p, 0.f);
        env_i = fmaxf(-p, 0.f);
    } else if (i < 13) {
        const float v = sv[i + 4] + pert[b * NN + i + 4];   // valences_eval[i-9]
        gate_e = 1.f / (1.f + __expf(-1.5f * v));           // sigmoid(ALPHA*v)
        gate_i = 1.f / (1.f + __expf(0.75f * v));           // sigmoid(-BETA*v)
        const float sum_act = sv[9] + sv[10] + sv[11] + sv[12];
        const float other = sum_act - sv[i];
        lat = 3.0f * other / (0.3f + other + 1e-6f);        // LAT_INHIB/(DIV_SIGMA+..)
        mask = feas[b * 4 + (i - 9)];
    }

    const float te = gate_e * sum_p + env_e;
    const float ti = gate_i * sum_n + lat + env_i;
    const float si = sv[i];

    const float dS = (-0.15f * si
                      + (1.0f - si) * fmaxf(te, 0.f)
                      - (0.1f + si) * fmaxf(ti, 0.f)) * 1.25f;   // /TAU

    // nontemporal: don't let the 17.8 MB write stream evict W lines from L3
    __builtin_nontemporal_store(dS * mask, out + t);
}

extern "C" void kernel_launch(void* const* d_in, const int* in_sizes, int n_in,
                              void* d_out, int out_size, void* d_ws, size_t ws_size,
                              hipStream_t stream)
{
    // setup_inputs order: t, state, W_pos, W_neg, feasibility, perturbation
    const float* state = (const float*)d_in[1];
    const float* W_pos = (const float*)d_in[2];
    const float* W_neg = (const float*)d_in[3];
    const float* feas  = (const float*)d_in[4];
    const float* pert  = (const float*)d_in[5];
    float* out = (float*)d_out;

    const int total = B_AGENTS * NN;            // 4456448, divisible by 256
    const int block = 256;
    const int grid = total / block;
    grossberg_kernel<<<grid, block, 0, stream>>>(state, W_pos, W_neg, feas, pert, out);
}